// Round 5
// baseline (200.641 us; speedup 1.0000x reference)
//
#include <hip/hip_runtime.h>
#include <math.h>

#define NN 20000
#define RR 32
#define HH 64
#define CC 8
#define EE 640000
#define HSTRIP 80

// ---------------------------------------------------------------- CSR build
__global__ __launch_bounds__(256) void k_zero(int* __restrict__ cnt) {
    int i = blockIdx.x * 256 + threadIdx.x;
    if (i < NN) cnt[i] = 0;
}

// 4 edges per thread, int4 loads (EE % 4 == 0)
__global__ __launch_bounds__(256) void k_hist(const int* __restrict__ ei,
                                              int* __restrict__ cnt) {
    int e = (blockIdx.x * 256 + threadIdx.x) * 4;
    if (e >= EE) return;
    int4 d = *(const int4*)(ei + EE + e);
    atomicAdd(&cnt[d.x], 1);
    atomicAdd(&cnt[d.y], 1);
    atomicAdd(&cnt[d.z], 1);
    atomicAdd(&cnt[d.w], 1);
}

// single-block scan: 1024 threads x 20 elements each (20480 >= NN)
#define SCAN_PER 20
__global__ __launch_bounds__(1024) void k_scan(const int* __restrict__ cnt,
                                               int* __restrict__ off,
                                               int* __restrict__ cur) {
    int tid = threadIdx.x;
    int base = tid * SCAN_PER;
    int v[SCAN_PER];
    int sum = 0;
    #pragma unroll
    for (int u = 0; u < SCAN_PER; u++) {
        int idx = base + u;
        v[u] = (idx < NN) ? cnt[idx] : 0;
        sum += v[u];
    }
    int lane = tid & 63, wv = tid >> 6;
    int s = sum;
    #pragma unroll
    for (int st = 1; st < 64; st <<= 1) {
        int t = __shfl_up(s, st, 64);
        if (lane >= st) s += t;
    }
    __shared__ int wsum[16];
    if (lane == 63) wsum[wv] = s;
    __syncthreads();
    if (wv == 0 && lane < 16) {
        int ws = wsum[lane];
        #pragma unroll
        for (int st = 1; st < 16; st <<= 1) {
            int t = __shfl_up(ws, st, 16);
            if (lane >= st) ws += t;
        }
        wsum[lane] = ws;
    }
    __syncthreads();
    int wbase = (wv > 0) ? wsum[wv - 1] : 0;
    int run = wbase + s - sum;
    #pragma unroll
    for (int u = 0; u < SCAN_PER; u++) {
        int idx = base + u;
        if (idx < NN) {
            cur[idx] = run;
            run += v[u];
            off[idx + 1] = run;
        }
    }
    if (tid == 0) off[0] = 0;
}

// 4 edges per thread, int4 loads
__global__ __launch_bounds__(256) void k_scatter(const int* __restrict__ ei,
                                                 const int* __restrict__ et,
                                                 int* __restrict__ cur,
                                                 unsigned* __restrict__ pk) {
    int e = (blockIdx.x * 256 + threadIdx.x) * 4;
    if (e >= EE) return;
    int4 sv = *(const int4*)(ei + e);
    int4 dv = *(const int4*)(ei + EE + e);
    int4 rv = *(const int4*)(et + e);
    pk[atomicAdd(&cur[dv.x], 1)] = (unsigned)sv.x | ((unsigned)rv.x << 15);
    pk[atomicAdd(&cur[dv.y], 1)] = (unsigned)sv.y | ((unsigned)rv.y << 15);
    pk[atomicAdd(&cur[dv.z], 1)] = (unsigned)sv.z | ((unsigned)rv.z << 15);
    pk[atomicAdd(&cur[dv.w], 1)] = (unsigned)sv.w | ((unsigned)rv.w << 15);
}

// ---------------------------------------------------------------- layer 1
// wave per dst node; 16-lane group g handles edge i+g; lane loads float4
// (16 B/lane, 1 KB per wave-instruction). Cross-group shfl_xor fold at end.
__global__ __launch_bounds__(256) void k_gather1(const unsigned* __restrict__ pk,
                                                 const int* __restrict__ off,
                                                 const float* __restrict__ W1,
                                                 const float* __restrict__ root1,
                                                 const float* __restrict__ bias1,
                                                 float* __restrict__ h) {
    int wid = (blockIdx.x * 256 + threadIdx.x) >> 6;
    int lane = threadIdx.x & 63;
    if (wid >= NN) return;
    int g = lane >> 4, p = lane & 15;
    float4 acc = make_float4(0.f, 0.f, 0.f, 0.f);
    int beg = off[wid], end = off[wid + 1];
    for (int i = beg; i < end; i += 16) {
        #pragma unroll
        for (int b = 0; b < 4; b++) {
            int e = i + b * 4 + g;
            unsigned q = pk[e < end ? e : beg];
            const float4* rp = (const float4*)(W1 + ((size_t)(q >> 15) * NN + (q & 0x7fffu)) * HH + p * 4);
            if (e < end) {
                float4 w = *rp;
                acc.x += w.x; acc.y += w.y; acc.z += w.z; acc.w += w.w;
            }
        }
    }
    #pragma unroll
    for (int m = 16; m < 64; m <<= 1) {
        acc.x += __shfl_xor(acc.x, m);
        acc.y += __shfl_xor(acc.y, m);
        acc.z += __shfl_xor(acc.z, m);
        acc.w += __shfl_xor(acc.w, m);
    }
    if (g == 0) {
        float4 rv = *(const float4*)(root1 + (size_t)wid * HH + p * 4);
        float4 bv = *(const float4*)(bias1 + p * 4);
        float4 res;
        res.x = fmaxf(acc.x + rv.x + bv.x, 0.f);
        res.y = fmaxf(acc.y + rv.y + bv.y, 0.f);
        res.z = fmaxf(acc.z + rv.z + bv.z, 0.f);
        res.w = fmaxf(acc.w + rv.w + bv.w, 0.f);
        *(float4*)(h + (size_t)wid * HH + p * 4) = res;
    }
}

// ---------------------------------------------------------------- layer 2
// thread (r,c) = tid keeps W2[r][:,c] in 64 registers; h row loads are
// wave-uniform broadcasts; hrel laid out [N][R*C] -> per-node store is one
// coalesced 1 KB block write.
__global__ __launch_bounds__(256) void k_hrel(const float* __restrict__ h,
                                              const float* __restrict__ W2,
                                              float* __restrict__ hrel) {
    int tid = threadIdx.x;
    int r = tid >> 3, c = tid & 7;
    float w[HH];
    #pragma unroll
    for (int k = 0; k < HH; k++) w[k] = W2[(size_t)r * HH * CC + k * CC + c];
    int n0 = blockIdx.x * HSTRIP;
    int n1 = (n0 + HSTRIP < NN) ? n0 + HSTRIP : NN;
    for (int n = n0; n < n1; n++) {
        const float* hp = h + (size_t)n * HH;
        float acc = 0.f;
        #pragma unroll
        for (int k = 0; k < HH; k += 4) {
            float4 hv = *(const float4*)(hp + k);
            acc += hv.x * w[k] + hv.y * w[k + 1] + hv.z * w[k + 2] + hv.w * w[k + 3];
        }
        hrel[(size_t)n * (RR * CC) + tid] = acc;
    }
}

// wave per dst node; gather hrel rows ([N][R][C] layout); fused root2+bias2+lsm
__global__ __launch_bounds__(256) void k_gather2(const unsigned* __restrict__ pk,
                                                 const int* __restrict__ off,
                                                 const float* __restrict__ h,
                                                 const float* __restrict__ hrel,
                                                 const float* __restrict__ root2,
                                                 const float* __restrict__ bias2,
                                                 float* __restrict__ out) {
    int wid = (blockIdx.x * 256 + threadIdx.x) >> 6;
    int lane = threadIdx.x & 63;
    if (wid >= NN) return;
    int kg = lane >> 3, c = lane & 7;
    float hn = h[(size_t)wid * HH + lane];
    float acc = 0.f;
    #pragma unroll
    for (int t = 0; t < 8; t++)
        acc += __shfl(hn, t, 8) * root2[(kg * 8 + t) * CC + c];
    int end = off[wid + 1];
    int i = off[wid] + kg;
    for (; i + 8 < end; i += 16) {
        unsigned p0 = pk[i], p1 = pk[i + 8];
        float v0 = hrel[((size_t)(p0 & 0x7fffu) * RR + (p0 >> 15)) * CC + c];
        float v1 = hrel[((size_t)(p1 & 0x7fffu) * RR + (p1 >> 15)) * CC + c];
        acc += v0 + v1;
    }
    for (; i < end; i += 8) {
        unsigned p = pk[i];
        acc += hrel[((size_t)(p & 0x7fffu) * RR + (p >> 15)) * CC + c];
    }
    acc += __shfl_xor(acc, 8);
    acc += __shfl_xor(acc, 16);
    acc += __shfl_xor(acc, 32);
    float x = acc + bias2[c];
    float m = x;
    m = fmaxf(m, __shfl_xor(m, 1));
    m = fmaxf(m, __shfl_xor(m, 2));
    m = fmaxf(m, __shfl_xor(m, 4));
    float ex = expf(x - m);
    ex += __shfl_xor(ex, 1);
    ex += __shfl_xor(ex, 2);
    ex += __shfl_xor(ex, 4);
    float l = m + logf(ex);
    if (lane < 8) out[(size_t)wid * CC + lane] = x - l;
}

extern "C" void kernel_launch(void* const* d_in, const int* in_sizes, int n_in,
                              void* d_out, int out_size, void* d_ws, size_t ws_size,
                              hipStream_t stream) {
    const int*   ei    = (const int*)d_in[0];    // [2, E]
    const int*   et    = (const int*)d_in[1];    // [E]
    const float* W1    = (const float*)d_in[3];  // [R, N, H]
    const float* root1 = (const float*)d_in[4];  // [N, H]
    const float* bias1 = (const float*)d_in[5];  // [H]
    const float* W2    = (const float*)d_in[6];  // [R, H, C]
    const float* root2 = (const float*)d_in[7];  // [H, C]
    const float* bias2 = (const float*)d_in[8];  // [C]
    float* out = (float*)d_out;

    char* base = (char*)d_ws;
    int*      cnt  = (int*)(base);                         // NN ints
    int*      cur  = (int*)(base + 80000);                 // NN ints
    int*      off  = (int*)(base + 160000);                // NN+1 ints
    unsigned* pk   = (unsigned*)(base + 240128);           // EE words
    float*    h    = (float*)(base + 2800128);             // NN*HH floats
    float*    hrel = (float*)(base + 7920128);             // NN*RR*CC floats
    // total ws use: 28,400,128 bytes

    k_zero   <<<(NN + 255) / 256, 256, 0, stream>>>(cnt);
    k_hist   <<<(EE / 4 + 255) / 256, 256, 0, stream>>>(ei, cnt);
    k_scan   <<<1, 1024, 0, stream>>>(cnt, off, cur);
    k_scatter<<<(EE / 4 + 255) / 256, 256, 0, stream>>>(ei, et, cur, pk);
    k_gather1<<<(NN * 64 + 255) / 256, 256, 0, stream>>>(pk, off, W1, root1, bias1, h);
    k_hrel   <<<(NN + HSTRIP - 1) / HSTRIP, 256, 0, stream>>>(h, W2, hrel);
    k_gather2<<<(NN * 64 + 255) / 256, 256, 0, stream>>>(pk, off, h, hrel, root2, bias2, out);
}

// Round 6
// 168.816 us; speedup vs baseline: 1.1885x; 1.1885x over previous
//
#include <hip/hip_runtime.h>
#include <math.h>

#define NN 20000
#define RR 32
#define HH 64
#define CC 8
#define EE 640000
#define TILE 10240

// ---------------------------------------------------------------- CSR build
__global__ __launch_bounds__(256) void k_zero(int* __restrict__ cnt) {
    int i = blockIdx.x * 256 + threadIdx.x;
    if (i < NN) cnt[i] = 0;
}

__global__ __launch_bounds__(256) void k_hist(const int* __restrict__ ei,
                                              int* __restrict__ cnt) {
    int e = blockIdx.x * 256 + threadIdx.x;
    if (e < EE) atomicAdd(&cnt[ei[EE + e]], 1);
}

// single block; coalesced loads via LDS; writes off[i] = exclusive prefix
__global__ __launch_bounds__(1024) void k_scan(const int* __restrict__ cnt,
                                               int* __restrict__ off) {
    __shared__ int s[TILE];      // 40 KB
    __shared__ int wsum[16];
    __shared__ int sbase_sh;
    int tid = threadIdx.x;
    if (tid == 0) sbase_sh = 0;
    __syncthreads();
    for (int t0 = 0; t0 < NN; t0 += TILE) {
        #pragma unroll
        for (int u = 0; u < TILE / 1024; u++) {
            int idx = t0 + u * 1024 + tid;
            s[u * 1024 + tid] = (idx < NN) ? cnt[idx] : 0;
        }
        __syncthreads();
        int base = tid * (TILE / 1024);
        int v[TILE / 1024];
        int sum = 0;
        #pragma unroll
        for (int u = 0; u < TILE / 1024; u++) { v[u] = s[base + u]; sum += v[u]; }
        int lane = tid & 63, wv = tid >> 6;
        int inc = sum;
        #pragma unroll
        for (int st = 1; st < 64; st <<= 1) {
            int t = __shfl_up(inc, st, 64);
            if (lane >= st) inc += t;
        }
        if (lane == 63) wsum[wv] = inc;
        __syncthreads();
        if (wv == 0 && lane < 16) {
            int ws = wsum[lane];
            #pragma unroll
            for (int st = 1; st < 16; st <<= 1) {
                int t = __shfl_up(ws, st, 16);
                if (lane >= st) ws += t;
            }
            wsum[lane] = ws;
        }
        __syncthreads();
        int run = sbase_sh + (wv ? wsum[wv - 1] : 0) + inc - sum;
        #pragma unroll
        for (int u = 0; u < TILE / 1024; u++) { s[base + u] = run; run += v[u]; }
        __syncthreads();
        #pragma unroll
        for (int u = 0; u < TILE / 1024; u++) {
            int idx = t0 + u * 1024 + tid;
            if (idx < NN) off[idx] = s[u * 1024 + tid];
        }
        if (tid == 1023) sbase_sh = run;   // total through this tile
        __syncthreads();
    }
}

// scatter: bump off[] in place. Post-kernel, off[d] = inclusive prefix.
__global__ __launch_bounds__(256) void k_scatter(const int* __restrict__ ei,
                                                 const int* __restrict__ et,
                                                 int* __restrict__ off,
                                                 unsigned* __restrict__ pk) {
    int e = blockIdx.x * 256 + threadIdx.x;
    if (e >= EE) return;
    int d = ei[EE + e];
    unsigned p = (unsigned)ei[e] | ((unsigned)et[e] << 15);
    int pos = atomicAdd(&off[d], 1);
    pk[pos] = p;
}

// ---------------------------------------------------------------- layer 1
// wave per dst node; lane owns h element; 8-deep load ILP.
// Epilogue fuses relu + the layer-2 root term: outr[n][c] = sum_k h[n][k]*root2[k][c]
__global__ __launch_bounds__(256) void k_gather1(const unsigned* __restrict__ pk,
                                                 const int* __restrict__ off,
                                                 const float* __restrict__ W1,
                                                 const float* __restrict__ root1,
                                                 const float* __restrict__ bias1,
                                                 const float* __restrict__ root2,
                                                 float* __restrict__ h,
                                                 float* __restrict__ outr) {
    int wid = (blockIdx.x * 256 + threadIdx.x) >> 6;
    int lane = threadIdx.x & 63;
    if (wid >= NN) return;
    float acc = root1[(size_t)wid * HH + lane] + bias1[lane];
    int i = wid ? off[wid - 1] : 0;
    int end = off[wid];
    for (; i + 8 <= end; i += 8) {
        float w[8];
        #pragma unroll
        for (int u = 0; u < 8; u++) {
            unsigned p = pk[i + u];
            w[u] = W1[((size_t)(p >> 15) * NN + (p & 0x7fffu)) * HH + lane];
        }
        acc += ((w[0] + w[1]) + (w[2] + w[3])) + ((w[4] + w[5]) + (w[6] + w[7]));
    }
    for (; i < end; ++i) {
        unsigned p = pk[i];
        acc += W1[((size_t)(p >> 15) * NN + (p & 0x7fffu)) * HH + lane];
    }
    float hv = fmaxf(acc, 0.0f);
    h[(size_t)wid * HH + lane] = hv;
    // ---- root2 epilogue: lane k holds h[k]; root2 row k is 32B contiguous
    float4 ra = *(const float4*)(root2 + lane * CC);
    float4 rb = *(const float4*)(root2 + lane * CC + 4);
    float a0 = hv * ra.x, a1 = hv * ra.y, a2 = hv * ra.z, a3 = hv * ra.w;
    float a4 = hv * rb.x, a5 = hv * rb.y, a6 = hv * rb.z, a7 = hv * rb.w;
    #pragma unroll
    for (int m = 1; m < 8; m <<= 1) {
        a0 += __shfl_xor(a0, m); a1 += __shfl_xor(a1, m);
        a2 += __shfl_xor(a2, m); a3 += __shfl_xor(a3, m);
        a4 += __shfl_xor(a4, m); a5 += __shfl_xor(a5, m);
        a6 += __shfl_xor(a6, m); a7 += __shfl_xor(a7, m);
    }
    int c = lane & 7;
    float v = a0;
    if (c == 1) v = a1;  if (c == 2) v = a2;  if (c == 3) v = a3;
    if (c == 4) v = a4;  if (c == 5) v = a5;  if (c == 6) v = a6;
    if (c == 7) v = a7;
    v += __shfl_xor(v, 8);
    v += __shfl_xor(v, 16);
    v += __shfl_xor(v, 32);
    if (lane < 8) outr[(size_t)wid * CC + lane] = v;
}

// ---------------------------------------------------------------- layer 2
// thread per (r, n): hrel[r][n][c] = sum_k h[n][k] * W2[r][k][c]   (round-3 form)
__global__ __launch_bounds__(256) void k_hrel(const float* __restrict__ h,
                                              const float* __restrict__ W2,
                                              float* __restrict__ hrel) {
    __shared__ float w2s[HH * CC];
    int r = blockIdx.y;
    int tid = threadIdx.x;
    w2s[tid]       = W2[(size_t)r * HH * CC + tid];
    w2s[tid + 256] = W2[(size_t)r * HH * CC + tid + 256];
    __syncthreads();
    int n = blockIdx.x * 256 + tid;
    if (n >= NN) return;
    const float* hp = h + (size_t)n * HH;
    float acc[CC] = {0, 0, 0, 0, 0, 0, 0, 0};
    #pragma unroll
    for (int k = 0; k < HH; k += 4) {
        float4 hv = *(const float4*)(hp + k);
        #pragma unroll
        for (int c = 0; c < CC; c++) {
            acc[c] += hv.x * w2s[(k + 0) * CC + c] + hv.y * w2s[(k + 1) * CC + c]
                    + hv.z * w2s[(k + 2) * CC + c] + hv.w * w2s[(k + 3) * CC + c];
        }
    }
    float* op = hrel + ((size_t)r * NN + n) * CC;
    *(float4*)(op)     = make_float4(acc[0], acc[1], acc[2], acc[3]);
    *(float4*)(op + 4) = make_float4(acc[4], acc[5], acc[6], acc[7]);
}

// wave per dst node; gather hrel rows; init from outr; fused bias2 + log-softmax
__global__ __launch_bounds__(256) void k_gather2(const unsigned* __restrict__ pk,
                                                 const int* __restrict__ off,
                                                 const float* __restrict__ hrel,
                                                 const float* __restrict__ outr,
                                                 const float* __restrict__ bias2,
                                                 float* __restrict__ out) {
    int wid = (blockIdx.x * 256 + threadIdx.x) >> 6;
    int lane = threadIdx.x & 63;
    if (wid >= NN) return;
    int kg = lane >> 3, c = lane & 7;
    float acc = (kg == 0) ? outr[(size_t)wid * CC + c] : 0.f;
    int beg = wid ? off[wid - 1] : 0;
    int end = off[wid];
    for (int i = beg + kg; i < end; i += 8) {
        unsigned p = pk[i];
        acc += hrel[((size_t)(p >> 15) * NN + (p & 0x7fffu)) * CC + c];
    }
    acc += __shfl_xor(acc, 8);
    acc += __shfl_xor(acc, 16);
    acc += __shfl_xor(acc, 32);
    float x = acc + bias2[c];
    float m = x;
    m = fmaxf(m, __shfl_xor(m, 1));
    m = fmaxf(m, __shfl_xor(m, 2));
    m = fmaxf(m, __shfl_xor(m, 4));
    float ex = expf(x - m);
    ex += __shfl_xor(ex, 1);
    ex += __shfl_xor(ex, 2);
    ex += __shfl_xor(ex, 4);
    float l = m + logf(ex);
    if (lane < 8) out[(size_t)wid * CC + lane] = x - l;
}

extern "C" void kernel_launch(void* const* d_in, const int* in_sizes, int n_in,
                              void* d_out, int out_size, void* d_ws, size_t ws_size,
                              hipStream_t stream) {
    const int*   ei    = (const int*)d_in[0];    // [2, E]
    const int*   et    = (const int*)d_in[1];    // [E]
    const float* W1    = (const float*)d_in[3];  // [R, N, H]
    const float* root1 = (const float*)d_in[4];  // [N, H]
    const float* bias1 = (const float*)d_in[5];  // [H]
    const float* W2    = (const float*)d_in[6];  // [R, H, C]
    const float* root2 = (const float*)d_in[7];  // [H, C]
    const float* bias2 = (const float*)d_in[8];  // [C]
    float* out = (float*)d_out;

    char* base = (char*)d_ws;
    int*      cnt  = (int*)(base);                // NN ints          [0, 80000)
    int*      off  = (int*)(base + 80000);        // NN ints          [80000, 160000)
    unsigned* pk   = (unsigned*)(base + 160000);  // EE words         [160000, 2720000)
    float*    h    = (float*)(base + 2720000);    // NN*HH floats     [2720000, 7840000)
    float*    outr = (float*)(base + 7840000);    // NN*CC floats     [7840000, 8480000)
    float*    hrel = (float*)(base + 8480000);    // RR*NN*CC floats  [8480000, 28960000)

    k_zero   <<<(NN + 255) / 256, 256, 0, stream>>>(cnt);
    k_hist   <<<(EE + 255) / 256, 256, 0, stream>>>(ei, cnt);
    k_scan   <<<1, 1024, 0, stream>>>(cnt, off);
    k_scatter<<<(EE + 255) / 256, 256, 0, stream>>>(ei, et, off, pk);
    k_gather1<<<(NN * 64 + 255) / 256, 256, 0, stream>>>(pk, off, W1, root1, bias1, root2, h, outr);
    k_hrel   <<<dim3((NN + 255) / 256, RR), 256, 0, stream>>>(h, W2, hrel);
    k_gather2<<<(NN * 64 + 255) / 256, 256, 0, stream>>>(pk, off, hrel, outr, bias2, out);
}